// Round 7
// baseline (157.563 us; speedup 1.0000x reference)
//
#include <hip/hip_runtime.h>

typedef unsigned short u16;
typedef unsigned int   u32;
typedef float f32x4 __attribute__((ext_vector_type(4)));
typedef u16   u16x8 __attribute__((ext_vector_type(8)));
typedef short s16x8 __attribute__((ext_vector_type(8)));
typedef u32   u32x4 __attribute__((ext_vector_type(4)));

#define B_  8
#define S_  4096
#define D_  2048
#define E_  64
#define M_  (B_ * S_)
#define BM  64
#define BK  64
#define KSPLIT 4
#define KLEN (D_ / KSPLIT)   // 512
#define NT  (KLEN / BK)      // 8 k-tiles per block

__device__ __forceinline__ u16 f2bf(float f) {
  u32 u = __builtin_bit_cast(u32, f);
  u += 0x7fffu + ((u >> 16) & 1u);
  return (u16)(u >> 16);
}
__device__ __forceinline__ float bf2f(u16 h) {
  u32 u = ((u32)h) << 16;
  return __builtin_bit_cast(float, u);
}
__device__ __forceinline__ u32 cvtpk_bf16(float a, float b) {
  u32 r;
  asm("v_cvt_pk_bf16_f32 %0, %1, %2" : "=v"(r) : "v"(a), "v"(b));
  return r;
}

// split 8 consecutive f32 into hi/lo bf16 fragments (RNE hi, residual lo)
__device__ __forceinline__ void split8v(f32x4 f0, f32x4 f1, s16x8& hi, s16x8& lo) {
  u32x4 h, l;
  float fa[8] = {f0[0], f0[1], f0[2], f0[3], f1[0], f1[1], f1[2], f1[3]};
  #pragma unroll
  for (int j = 0; j < 4; ++j) {
    float a = fa[2 * j], b = fa[2 * j + 1];
    u32 hw = cvtpk_bf16(a, b);
    float ra = a - __builtin_bit_cast(float, hw << 16);
    float rb = b - __builtin_bit_cast(float, hw & 0xffff0000u);
    l[j] = cvtpk_bf16(ra, rb);
    h[j] = hw;
  }
  hi = __builtin_bit_cast(s16x8, h);
  lo = __builtin_bit_cast(s16x8, l);
}

__device__ __forceinline__ void gload16(const void* g, void* l) {
  __builtin_amdgcn_global_load_lds(
      (const __attribute__((address_space(1))) void*)g,
      (__attribute__((address_space(3))) void*)l, 16, 0, 0);
}
__device__ __forceinline__ f32x4 mfma16(s16x8 a, s16x8 b, f32x4 c) {
  return __builtin_amdgcn_mfma_f32_16x16x32_bf16(a, b, c, 0, 0, 0);
}

// ---------------- merged prep: blocks 0-7 compaction, blocks 8+ W conversion ----
__launch_bounds__(1024)
__global__ void prep_kernel(const float* __restrict__ W,
                            u16* __restrict__ whiT, u16* __restrict__ wloT,
                            const int* __restrict__ idxs,
                            int* __restrict__ compact, int* __restrict__ posmap,
                            int* __restrict__ count) {
  __shared__ u32 flag[S_];
  __shared__ int wtot[16], wpre[16];
  const int t = threadIdx.x;

  if (blockIdx.x >= 8) {
    int i = (blockIdx.x - 8) * 1024 + t;   // 0 .. D*E-1
    int k = i >> 6;
    int e = i & 63;
    float w = W[i];
    u16 h = f2bf(w);
    u16 l = f2bf(w - bf2f(h));
    whiT[(size_t)e * D_ + k] = h;
    wloT[(size_t)e * D_ + k] = l;
    return;
  }

  const int b = blockIdx.x;
  const int lane = t & 63, wid = t >> 6;

  #pragma unroll
  for (int j = 0; j < 4; ++j) flag[t + j * 1024] = 0;
  __syncthreads();
  #pragma unroll
  for (int j = 0; j < 4; ++j) flag[idxs[b * S_ + t + j * 1024]] = 1;
  __syncthreads();

  int f[4], s = 0;
  #pragma unroll
  for (int j = 0; j < 4; ++j) { f[j] = (int)flag[t * 4 + j]; s += f[j]; }
  int inc = s;
  #pragma unroll
  for (int off = 1; off < 64; off <<= 1) {
    int v = __shfl_up(inc, off);
    if (lane >= off) inc += v;
  }
  if (lane == 63) wtot[wid] = inc;
  __syncthreads();
  if (t == 0) {
    int acc = 0;
    for (int w = 0; w < 16; ++w) { wpre[w] = acc; acc += wtot[w]; }
    count[b] = acc;
  }
  __syncthreads();
  int p = wpre[wid] + inc - s;
  #pragma unroll
  for (int j = 0; j < 4; ++j) {
    int g = t * 4 + j;
    if (f[j]) {
      compact[b * S_ + p] = g;
      posmap[b * S_ + g] = p;
      ++p;
    }
  }
}

// ---------------- GEMM: A double-buffered LDS (counted vmcnt), W direct from L2 ----
__launch_bounds__(256, 4)
__global__ void router_gemm(const float* __restrict__ A,      // [8][4096][2048]
                            const u16* __restrict__ WhiT,     // [64][2048]
                            const u16* __restrict__ WloT,
                            const int* __restrict__ compact,  // [8][4096]
                            const int* __restrict__ count,    // [8]
                            float* __restrict__ Cp) {         // [KSPLIT][8][4096][64]
  __shared__ __align__(16) float Asm[2][BM * BK];   // 2 x 16 KB (XOR-swizzled)

  const int b    = blockIdx.x >> 6;
  const int tile = blockIdx.x & 63;
  const int row0 = tile * BM;
  const int cnt  = count[b];
  if (row0 >= cnt) return;

  const int t    = threadIdx.x;
  const int lane = t & 63;
  const int wid  = t >> 6;
  const int fr   = lane & 15;
  const int fk   = lane >> 4;                // 0..3 (k-subgroup)
  const int kbeg = blockIdx.y * KLEN;

  // --- A staging source pointers (pre-swizzled global addresses, rule #21) ---
  const float* asrc[4];
  #pragma unroll
  for (int g = 0; g < 4; ++g) {
    int row = g * 16 + (t >> 4);
    int cb  = ((t & 15) * 16) ^ ((row & 7) << 4);
    int rr  = row0 + row; if (rr >= cnt) rr = cnt - 1;
    int grow = compact[b * S_ + rr];
    asrc[g] = A + ((size_t)b * S_ + grow) * D_ + kbeg + (cb >> 2);
  }

  // --- W fragment pointers: direct global (L2-resident), per-lane 16B ---
  const u16* wfh[4];
  const u16* wfl[4];
  #pragma unroll
  for (int n = 0; n < 4; ++n) {
    wfh[n] = WhiT + (size_t)(n * 16 + fr) * D_ + kbeg + fk * 8;
    wfl[n] = WloT + (size_t)(n * 16 + fr) * D_ + kbeg + fk * 8;
  }

  // --- A LDS read byte offsets (swizzled), static across k-iters ---
  const int arow = wid * 16 + fr;
  const int axr  = (arow & 7) << 4;
  u32 aoff[2][2];
  #pragma unroll
  for (int ks = 0; ks < 2; ++ks) {
    aoff[ks][0] = arow * 256 + ((ks * 128 + fk * 32) ^ axr);
    aoff[ks][1] = arow * 256 + ((ks * 128 + fk * 32 + 16) ^ axr);
  }

  f32x4 acc[4] = {};

  #define STAGE_A(buf, koff)                                                       \
    do {                                                                           \
      _Pragma("unroll")                                                            \
      for (int g = 0; g < 4; ++g)                                                  \
        gload16(asrc[g] + (koff), (char*)Asm[buf] + (size_t)(g * 256 + t) * 16);   \
    } while (0)

  // prologue: stage tile 0 into buf 0
  STAGE_A(0, 0);

  #pragma unroll 1
  for (int tt = 0; tt < NT; ++tt) {
    const int cur = tt & 1;
    const int koff = tt * BK;

    // 1) W fragments for CURRENT tile -> registers (16 dwordx4 from L2)
    s16x8 wh[2][4], wl[2][4];
    #pragma unroll
    for (int ks = 0; ks < 2; ++ks)
      #pragma unroll
      for (int n = 0; n < 4; ++n) {
        wh[ks][n] = *(const s16x8*)(wfh[n] + koff + ks * 32);
        wl[ks][n] = *(const s16x8*)(wfl[n] + koff + ks * 32);
      }
    __builtin_amdgcn_sched_barrier(0);   // pin order: W loads before A stage

    // 2) prefetch NEXT A tile into the other buffer (stays in flight)
    if (tt + 1 < NT) {
      STAGE_A(cur ^ 1, koff + BK);
      // newest outstanding: 16 W + 4 A(next). All older (incl. A(cur)) drained:
      asm volatile("s_waitcnt vmcnt(20)" ::: "memory");
    } else {
      // no stage issued: newest outstanding = 16 W; drain A(cur):
      asm volatile("s_waitcnt vmcnt(16)" ::: "memory");
    }
    __builtin_amdgcn_s_barrier();        // all waves: A(cur) landed
    __builtin_amdgcn_sched_barrier(0);

    // 3) compute tile from Asm[cur] + W regs
    {
      const char* aL = (const char*)Asm[cur];
      #pragma unroll
      for (int ks = 0; ks < 2; ++ks) {
        f32x4 af0 = *(const f32x4*)(aL + aoff[ks][0]);
        f32x4 af1 = *(const f32x4*)(aL + aoff[ks][1]);
        s16x8 ah, al;
        split8v(af0, af1, ah, al);
        #pragma unroll
        for (int n = 0; n < 4; ++n) {
          acc[n] = mfma16(al, wh[ks][n], acc[n]);
          acc[n] = mfma16(ah, wl[ks][n], acc[n]);
          acc[n] = mfma16(ah, wh[ks][n], acc[n]);
        }
      }
    }
    __builtin_amdgcn_s_barrier();        // reads done before buf[cur] rewritten at tt+2
  }
  #undef STAGE_A

  // epilogue: C/D layout col = lane&15, row = (lane>>4)*4 + reg
  float* cb = Cp + ((size_t)blockIdx.y * B_ + b) * S_ * E_;
  const int orow = row0 + wid * 16 + (lane >> 4) * 4;
  #pragma unroll
  for (int n = 0; n < 4; ++n) {
    int ocol = n * 16 + fr;
    #pragma unroll
    for (int r = 0; r < 4; ++r)
      cb[(size_t)(orow + r) * E_ + ocol] = acc[n][r];
  }
}

// ---------------- top-4 + softmax per UNIQUE row -> mask ----------------
__launch_bounds__(256)
__global__ void topk_unique(const float* __restrict__ Cp,     // [KSPLIT][8][4096][64]
                            const int* __restrict__ count,    // [8]
                            float* __restrict__ mask) {       // [8][4096][64]
  const int b    = blockIdx.x >> 10;
  const int p    = (blockIdx.x & 1023) * 4 + (threadIdx.x >> 6);
  if (p >= count[b]) return;
  const int lane = threadIdx.x & 63;

  size_t off = ((size_t)b * S_ + p) * E_ + lane;
  float cur = 0.f;
  #pragma unroll
  for (int ps = 0; ps < KSPLIT; ++ps)
    cur += Cp[(size_t)ps * M_ * E_ + off];

  float vals[4];
  int   inds[4];
  #pragma unroll
  for (int tk = 0; tk < 4; ++tk) {
    float mv = cur;
    int   mi = lane;
    #pragma unroll
    for (int off2 = 32; off2 > 0; off2 >>= 1) {
      float ov = __shfl_xor(mv, off2);
      int   oi = __shfl_xor(mi, off2);
      if (ov > mv || (ov == mv && oi < mi)) { mv = ov; mi = oi; }  // tie -> smaller index
    }
    vals[tk] = mv;
    inds[tk] = mi;
    if (lane == mi) cur = -INFINITY;
  }

  float w[4], ssum = 0.f;
  #pragma unroll
  for (int tk = 0; tk < 4; ++tk) { w[tk] = __expf(vals[tk] - vals[0]); ssum += w[tk]; }
  float inv = 1.f / ssum;
  float o = 0.f;
  #pragma unroll
  for (int tk = 0; tk < 4; ++tk)
    if (lane == inds[tk]) o = w[tk] * inv;

  mask[off] = o;
}

// ---------------- scatter: out[r] = mask[b][posmap[idxs[r]]] ----------------
__launch_bounds__(256)
__global__ void scatter_kernel(const float* __restrict__ mask,   // [8][4096][64]
                               const int* __restrict__ idxs,     // [8][4096]
                               const int* __restrict__ posmap,   // [8][4096]
                               float* __restrict__ out) {        // [8][4096][64]
  const int lane = threadIdx.x & 63;
  const int wid  = threadIdx.x >> 6;
  const int r    = blockIdx.x * 4 + wid;
  const int b    = r >> 12;
  const int p    = posmap[(size_t)b * S_ + idxs[r]];
  out[(size_t)r * E_ + lane] = mask[((size_t)b * S_ + p) * E_ + lane];
}

// ---------------- host ----------------
extern "C" void kernel_launch(void* const* d_in, const int* in_sizes, int n_in,
                              void* d_out, int out_size, void* d_ws, size_t ws_size,
                              hipStream_t stream) {
  const float* hidden = (const float*)d_in[0];
  const int*   idxs   = (const int*)d_in[1];
  const float* W      = (const float*)d_in[2];
  float* out = (float*)d_out;

  // ws: Cp [4][8][4096][64] f32 (32MB) | mask (8MB) | WhiT (256KB) | WloT (256KB)
  //     | compact (128KB) | posmap (128KB) | count (32B)
  char* wsp = (char*)d_ws;
  float* Cp   = (float*)wsp;                     wsp += (size_t)KSPLIT * M_ * E_ * 4;
  float* mask = (float*)wsp;                     wsp += (size_t)M_ * E_ * 4;
  u16* whiT = (u16*)wsp;                         wsp += (size_t)E_ * D_ * 2;
  u16* wloT = (u16*)wsp;                         wsp += (size_t)E_ * D_ * 2;
  int* compact = (int*)wsp;                      wsp += (size_t)M_ * 4;
  int* posmap  = (int*)wsp;                      wsp += (size_t)M_ * 4;
  int* count   = (int*)wsp;

  prep_kernel<<<8 + (D_ * E_) / 1024, 1024, 0, stream>>>(W, whiT, wloT, idxs,
                                                          compact, posmap, count);
  dim3 g(B_ * 64, KSPLIT);
  router_gemm<<<g, 256, 0, stream>>>(hidden, whiT, wloT, compact, count, Cp);
  topk_unique<<<B_ * 1024, 256, 0, stream>>>(Cp, count, mask);
  scatter_kernel<<<M_ / 4, 256, 0, stream>>>(mask, idxs, posmap, out);
}

// Round 8
// 79.671 us; speedup vs baseline: 1.9777x; 1.9777x over previous
//
#include <hip/hip_runtime.h>

typedef unsigned short u16;
typedef unsigned int   u32;
typedef float f32x4 __attribute__((ext_vector_type(4)));
typedef u16   u16x8 __attribute__((ext_vector_type(8)));
typedef short s16x8 __attribute__((ext_vector_type(8)));
typedef u32   u32x4 __attribute__((ext_vector_type(4)));

#define B_  8
#define S_  4096
#define D_  2048
#define E_  64
#define M_  (B_ * S_)
#define BM  64
#define BK  32
#define KSPLIT 4
#define KLEN (D_ / KSPLIT)   // 512
#define NT  (KLEN / BK)      // 16 k-tiles per block (even)

__device__ __forceinline__ u16 f2bf(float f) {
  u32 u = __builtin_bit_cast(u32, f);
  u += 0x7fffu + ((u >> 16) & 1u);
  return (u16)(u >> 16);
}
__device__ __forceinline__ float bf2f(u16 h) {
  u32 u = ((u32)h) << 16;
  return __builtin_bit_cast(float, u);
}
__device__ __forceinline__ u32 cvtpk_bf16(float a, float b) {
  u32 r;
  asm("v_cvt_pk_bf16_f32 %0, %1, %2" : "=v"(r) : "v"(a), "v"(b));
  return r;
}

// split 8 consecutive f32 into hi/lo bf16 fragments (RNE hi, residual lo)
__device__ __forceinline__ void split8v(f32x4 f0, f32x4 f1, s16x8& hi, s16x8& lo) {
  u32x4 h, l;
  float fa[8] = {f0[0], f0[1], f0[2], f0[3], f1[0], f1[1], f1[2], f1[3]};
  #pragma unroll
  for (int j = 0; j < 4; ++j) {
    float a = fa[2 * j], b = fa[2 * j + 1];
    u32 hw = cvtpk_bf16(a, b);
    float ra = a - __builtin_bit_cast(float, hw << 16);
    float rb = b - __builtin_bit_cast(float, hw & 0xffff0000u);
    l[j] = cvtpk_bf16(ra, rb);
    h[j] = hw;
  }
  hi = __builtin_bit_cast(s16x8, h);
  lo = __builtin_bit_cast(s16x8, l);
}

__device__ __forceinline__ void gload16(const void* g, void* l) {
  __builtin_amdgcn_global_load_lds(
      (const __attribute__((address_space(1))) void*)g,
      (__attribute__((address_space(3))) void*)l, 16, 0, 0);
}
__device__ __forceinline__ f32x4 mfma16(s16x8 a, s16x8 b, f32x4 c) {
  return __builtin_amdgcn_mfma_f32_16x16x32_bf16(a, b, c, 0, 0, 0);
}

// ---------------- merged prep: blocks 0-7 compaction, blocks 8+ W conversion ----
__launch_bounds__(1024)
__global__ void prep_kernel(const float* __restrict__ W,
                            u16* __restrict__ whiT, u16* __restrict__ wloT,
                            const int* __restrict__ idxs,
                            int* __restrict__ compact, int* __restrict__ posmap,
                            int* __restrict__ count) {
  __shared__ u32 flag[S_];
  __shared__ int wtot[16], wpre[16];
  const int t = threadIdx.x;

  if (blockIdx.x >= 8) {
    int i = (blockIdx.x - 8) * 1024 + t;   // 0 .. D*E-1
    int k = i >> 6;
    int e = i & 63;
    float w = W[i];
    u16 h = f2bf(w);
    u16 l = f2bf(w - bf2f(h));
    whiT[(size_t)e * D_ + k] = h;
    wloT[(size_t)e * D_ + k] = l;
    return;
  }

  const int b = blockIdx.x;
  const int lane = t & 63, wid = t >> 6;

  #pragma unroll
  for (int j = 0; j < 4; ++j) flag[t + j * 1024] = 0;
  __syncthreads();
  #pragma unroll
  for (int j = 0; j < 4; ++j) flag[idxs[b * S_ + t + j * 1024]] = 1;
  __syncthreads();

  int f[4], s = 0;
  #pragma unroll
  for (int j = 0; j < 4; ++j) { f[j] = (int)flag[t * 4 + j]; s += f[j]; }
  int inc = s;
  #pragma unroll
  for (int off = 1; off < 64; off <<= 1) {
    int v = __shfl_up(inc, off);
    if (lane >= off) inc += v;
  }
  if (lane == 63) wtot[wid] = inc;
  __syncthreads();
  if (t == 0) {
    int acc = 0;
    for (int w = 0; w < 16; ++w) { wpre[w] = acc; acc += wtot[w]; }
    count[b] = acc;
  }
  __syncthreads();
  int p = wpre[wid] + inc - s;
  #pragma unroll
  for (int j = 0; j < 4; ++j) {
    int g = t * 4 + j;
    if (f[j]) {
      compact[b * S_ + p] = g;
      posmap[b * S_ + g] = p;
      ++p;
    }
  }
}

// ---------------- GEMM: BK=32, both operands double-buffered, counted vmcnt ----
// LDS 32 KB total -> 5 blocks/CU. W packed per-e row: [hi k0..31 | lo k0..31] 128B.
__launch_bounds__(256, 5)
__global__ void router_gemm(const float* __restrict__ A,      // [8][4096][2048]
                            const u16* __restrict__ WhiT,     // [64][2048]
                            const u16* __restrict__ WloT,
                            const int* __restrict__ compact,  // [8][4096]
                            const int* __restrict__ count,    // [8]
                            float* __restrict__ Cp) {         // [KSPLIT][8][4096][64]
  __shared__ __align__(16) float Asm[2][BM * BK];       // 2 x 8 KB (swizzled)
  __shared__ __align__(16) u16  Wsm[2][E_ * BK * 2];    // 2 x 8 KB (hi|lo, swizzled)

  const int b    = blockIdx.x >> 6;
  const int tile = blockIdx.x & 63;
  const int row0 = tile * BM;
  const int cnt  = count[b];
  if (row0 >= cnt) return;

  const int t    = threadIdx.x;
  const int lane = t & 63;
  const int wid  = t >> 6;
  const int fr   = lane & 15;
  const int fk   = lane >> 4;                // 0..3 (k-subgroup)
  const int kbeg = blockIdx.y * KLEN;

  // --- A staging sources (pre-swizzled global addr; LDS dest linear, rule #21) ---
  // slot s covers LDS bytes (s*256+t)*16: row = s*32 + (t>>3), phys 16B-slot = t&7,
  // logical 16B-slot l = (t&7) ^ (row&7)  -> floats l*4
  const float* asrc[2];
  #pragma unroll
  for (int s = 0; s < 2; ++s) {
    int row = s * 32 + (t >> 3);
    int l   = (t & 7) ^ (row & 7);
    int rr  = row0 + row; if (rr >= cnt) rr = cnt - 1;
    int grow = compact[b * S_ + rr];
    asrc[s] = A + ((size_t)b * S_ + grow) * D_ + kbeg + l * 4;
  }
  // --- W staging sources: row e = 128B [hi(64B)|lo(64B)], logical slot l = (t&7)^(e&7);
  // l<4 -> hi k-group l, l>=4 -> lo k-group l-4
  const u16* wsrc[2];
  #pragma unroll
  for (int s = 0; s < 2; ++s) {
    int e = s * 32 + (t >> 3);
    int l = (t & 7) ^ (e & 7);
    const u16* base = (l < 4) ? WhiT : WloT;
    wsrc[s] = base + (size_t)e * D_ + kbeg + (l & 3) * 8;
  }

  // --- LDS read byte offsets (swizzled), static ---
  const int arow = wid * 16 + fr;
  const int axr  = (arow & 7) << 4;
  const u32 aoff0 = arow * 128 + ((fk * 32)      ^ axr);
  const u32 aoff1 = arow * 128 + ((fk * 32 + 16) ^ axr);
  u32 whoff[4], wloff[4];
  #pragma unroll
  for (int n = 0; n < 4; ++n) {
    int e  = n * 16 + fr;
    int xe = (e & 7) << 4;
    whoff[n] = e * 128 + (((fk)     * 16) ^ xe);
    wloff[n] = e * 128 + (((fk + 4) * 16) ^ xe);
  }

  f32x4 acc[4] = {};

  #define STAGE(buf, koff)                                                        \
    do {                                                                          \
      gload16(asrc[0] + (koff), (char*)Asm[buf] + (size_t)t * 16);                \
      gload16(asrc[1] + (koff), (char*)Asm[buf] + (size_t)(256 + t) * 16);        \
      gload16(wsrc[0] + (koff), (char*)Wsm[buf] + (size_t)t * 16);                \
      gload16(wsrc[1] + (koff), (char*)Wsm[buf] + (size_t)(256 + t) * 16);        \
    } while (0)

  #define COMPUTE(buf)                                                            \
    do {                                                                          \
      const char* aL = (const char*)Asm[buf];                                     \
      const char* wL = (const char*)Wsm[buf];                                     \
      f32x4 af0 = *(const f32x4*)(aL + aoff0);                                    \
      f32x4 af1 = *(const f32x4*)(aL + aoff1);                                    \
      s16x8 ah, al;                                                               \
      split8v(af0, af1, ah, al);                                                  \
      _Pragma("unroll")                                                           \
      for (int n = 0; n < 4; ++n) {                                               \
        s16x8 wh = *(const s16x8*)(wL + whoff[n]);                                \
        s16x8 wl = *(const s16x8*)(wL + wloff[n]);                                \
        acc[n] = mfma16(al, wh, acc[n]);                                          \
        acc[n] = mfma16(ah, wl, acc[n]);                                          \
        acc[n] = mfma16(ah, wh, acc[n]);                                          \
      }                                                                           \
    } while (0)

  // prologue: tile 0 -> buf 0
  STAGE(0, 0);

  #pragma unroll 1
  for (int tt = 0; tt < NT; tt += 2) {
    // ---- even tile (buf 0) ----
    if (tt + 1 < NT) {
      STAGE(1, (tt + 1) * BK);                          // prefetch stays in flight
      asm volatile("s_waitcnt vmcnt(4)" ::: "memory");  // drain only prior tile's 4
    } else {
      asm volatile("s_waitcnt vmcnt(0)" ::: "memory");
    }
    __builtin_amdgcn_s_barrier();
    __builtin_amdgcn_sched_barrier(0);
    COMPUTE(0);
    __builtin_amdgcn_s_barrier();
    __builtin_amdgcn_sched_barrier(0);

    // ---- odd tile (buf 1) ----
    if (tt + 2 < NT) {
      STAGE(0, (tt + 2) * BK);
      asm volatile("s_waitcnt vmcnt(4)" ::: "memory");
    } else {
      asm volatile("s_waitcnt vmcnt(0)" ::: "memory");
    }
    __builtin_amdgcn_s_barrier();
    __builtin_amdgcn_sched_barrier(0);
    COMPUTE(1);
    __builtin_amdgcn_s_barrier();
    __builtin_amdgcn_sched_barrier(0);
  }
  #undef STAGE
  #undef COMPUTE

  // epilogue: C/D layout col = lane&15, row = (lane>>4)*4 + reg
  float* cb = Cp + ((size_t)blockIdx.y * B_ + b) * S_ * E_;
  const int orow = row0 + wid * 16 + (lane >> 4) * 4;
  #pragma unroll
  for (int n = 0; n < 4; ++n) {
    int ocol = n * 16 + fr;
    #pragma unroll
    for (int r = 0; r < 4; ++r)
      cb[(size_t)(orow + r) * E_ + ocol] = acc[n][r];
  }
}

// ---------------- top-4 + softmax per UNIQUE row -> mask ----------------
__launch_bounds__(256)
__global__ void topk_unique(const float* __restrict__ Cp,     // [KSPLIT][8][4096][64]
                            const int* __restrict__ count,    // [8]
                            float* __restrict__ mask) {       // [8][4096][64]
  const int b    = blockIdx.x >> 10;
  const int p    = (blockIdx.x & 1023) * 4 + (threadIdx.x >> 6);
  if (p >= count[b]) return;
  const int lane = threadIdx.x & 63;

  size_t off = ((size_t)b * S_ + p) * E_ + lane;
  float cur = 0.f;
  #pragma unroll
  for (int ps = 0; ps < KSPLIT; ++ps)
    cur += Cp[(size_t)ps * M_ * E_ + off];

  float vals[4];
  int   inds[4];
  #pragma unroll
  for (int tk = 0; tk < 4; ++tk) {
    float mv = cur;
    int   mi = lane;
    #pragma unroll
    for (int off2 = 32; off2 > 0; off2 >>= 1) {
      float ov = __shfl_xor(mv, off2);
      int   oi = __shfl_xor(mi, off2);
      if (ov > mv || (ov == mv && oi < mi)) { mv = ov; mi = oi; }  // tie -> smaller index
    }
    vals[tk] = mv;
    inds[tk] = mi;
    if (lane == mi) cur = -INFINITY;
  }

  float w[4], ssum = 0.f;
  #pragma unroll
  for (int tk = 0; tk < 4; ++tk) { w[tk] = __expf(vals[tk] - vals[0]); ssum += w[tk]; }
  float inv = 1.f / ssum;
  float o = 0.f;
  #pragma unroll
  for (int tk = 0; tk < 4; ++tk)
    if (lane == inds[tk]) o = w[tk] * inv;

  mask[off] = o;
}

// ---------------- scatter: out[r] = mask[b][posmap[idxs[r]]] ----------------
__launch_bounds__(256)
__global__ void scatter_kernel(const float* __restrict__ mask,   // [8][4096][64]
                               const int* __restrict__ idxs,     // [8][4096]
                               const int* __restrict__ posmap,   // [8][4096]
                               float* __restrict__ out) {        // [8][4096][64]
  const int lane = threadIdx.x & 63;
  const int wid  = threadIdx.x >> 6;
  const int r    = blockIdx.x * 4 + wid;
  const int b    = r >> 12;
  const int p    = posmap[(size_t)b * S_ + idxs[r]];
  out[(size_t)r * E_ + lane] = mask[((size_t)b * S_ + p) * E_ + lane];
}

// ---------------- host ----------------
extern "C" void kernel_launch(void* const* d_in, const int* in_sizes, int n_in,
                              void* d_out, int out_size, void* d_ws, size_t ws_size,
                              hipStream_t stream) {
  const float* hidden = (const float*)d_in[0];
  const int*   idxs   = (const int*)d_in[1];
  const float* W      = (const float*)d_in[2];
  float* out = (float*)d_out;

  // ws: Cp [4][8][4096][64] f32 (32MB) | mask (8MB) | WhiT (256KB) | WloT (256KB)
  //     | compact (128KB) | posmap (128KB) | count (32B)
  char* wsp = (char*)d_ws;
  float* Cp   = (float*)wsp;                     wsp += (size_t)KSPLIT * M_ * E_ * 4;
  float* mask = (float*)wsp;                     wsp += (size_t)M_ * E_ * 4;
  u16* whiT = (u16*)wsp;                         wsp += (size_t)E_ * D_ * 2;
  u16* wloT = (u16*)wsp;                         wsp += (size_t)E_ * D_ * 2;
  int* compact = (int*)wsp;                      wsp += (size_t)M_ * 4;
  int* posmap  = (int*)wsp;                      wsp += (size_t)M_ * 4;
  int* count   = (int*)wsp;

  prep_kernel<<<8 + (D_ * E_) / 1024, 1024, 0, stream>>>(W, whiT, wloT, idxs,
                                                          compact, posmap, count);
  dim3 g(B_ * 64, KSPLIT);
  router_gemm<<<g, 256, 0, stream>>>(hidden, whiT, wloT, compact, count, Cp);
  topk_unique<<<B_ * 1024, 256, 0, stream>>>(Cp, count, mask);
  scatter_kernel<<<M_ / 4, 256, 0, stream>>>(mask, idxs, posmap, out);
}

// Round 9
// 59.113 us; speedup vs baseline: 2.6655x; 1.3478x over previous
//
#include <hip/hip_runtime.h>

typedef unsigned short u16;
typedef unsigned int   u32;
typedef float f32x4 __attribute__((ext_vector_type(4)));
typedef u16   u16x8 __attribute__((ext_vector_type(8)));
typedef short s16x8 __attribute__((ext_vector_type(8)));
typedef u32   u32x4 __attribute__((ext_vector_type(4)));

#define B_  8
#define S_  4096
#define D_  2048
#define E_  64
#define M_  (B_ * S_)
#define BM  32            // rows per block
#define BK  64
#define KHALF 1024        // per wave-pair K range
#define NT  (KHALF / BK)  // 16 k-tiles per half

__device__ __forceinline__ u16 f2bf(float f) {
  u32 u = __builtin_bit_cast(u32, f);
  u += 0x7fffu + ((u >> 16) & 1u);
  return (u16)(u >> 16);
}
__device__ __forceinline__ float bf2f(u16 h) {
  u32 u = ((u32)h) << 16;
  return __builtin_bit_cast(float, u);
}
__device__ __forceinline__ u32 cvtpk_bf16(float a, float b) {
  u32 r;
  asm("v_cvt_pk_bf16_f32 %0, %1, %2" : "=v"(r) : "v"(a), "v"(b));
  return r;
}

// split 8 consecutive f32 into hi/lo bf16 fragments (RNE hi, residual lo)
__device__ __forceinline__ void split8v(f32x4 f0, f32x4 f1, s16x8& hi, s16x8& lo) {
  u32x4 h, l;
  float fa[8] = {f0[0], f0[1], f0[2], f0[3], f1[0], f1[1], f1[2], f1[3]};
  #pragma unroll
  for (int j = 0; j < 4; ++j) {
    float a = fa[2 * j], b = fa[2 * j + 1];
    u32 hw = cvtpk_bf16(a, b);
    float ra = a - __builtin_bit_cast(float, hw << 16);
    float rb = b - __builtin_bit_cast(float, hw & 0xffff0000u);
    l[j] = cvtpk_bf16(ra, rb);
    h[j] = hw;
  }
  hi = __builtin_bit_cast(s16x8, h);
  lo = __builtin_bit_cast(s16x8, l);
}

__device__ __forceinline__ void gload16(const void* g, void* l) {
  __builtin_amdgcn_global_load_lds(
      (const __attribute__((address_space(1))) void*)g,
      (__attribute__((address_space(3))) void*)l, 16, 0, 0);
}
__device__ __forceinline__ f32x4 mfma16(s16x8 a, s16x8 b, f32x4 c) {
  return __builtin_amdgcn_mfma_f32_16x16x32_bf16(a, b, c, 0, 0, 0);
}

// ---------------- merged prep: blocks 0-7 compaction, blocks 8+ W conversion ----
__launch_bounds__(1024)
__global__ void prep_kernel(const float* __restrict__ W,
                            u16* __restrict__ whiT, u16* __restrict__ wloT,
                            const int* __restrict__ idxs,
                            int* __restrict__ compact, int* __restrict__ posmap,
                            int* __restrict__ count) {
  __shared__ u32 flag[S_];
  __shared__ int wtot[16], wpre[16];
  const int t = threadIdx.x;

  if (blockIdx.x >= 8) {
    int i = (blockIdx.x - 8) * 1024 + t;   // 0 .. D*E-1
    int k = i >> 6;
    int e = i & 63;
    float w = W[i];
    u16 h = f2bf(w);
    u16 l = f2bf(w - bf2f(h));
    whiT[(size_t)e * D_ + k] = h;
    wloT[(size_t)e * D_ + k] = l;
    return;
  }

  const int b = blockIdx.x;
  const int lane = t & 63, wid = t >> 6;

  #pragma unroll
  for (int j = 0; j < 4; ++j) flag[t + j * 1024] = 0;
  __syncthreads();
  #pragma unroll
  for (int j = 0; j < 4; ++j) flag[idxs[b * S_ + t + j * 1024]] = 1;
  __syncthreads();

  int f[4], s = 0;
  #pragma unroll
  for (int j = 0; j < 4; ++j) { f[j] = (int)flag[t * 4 + j]; s += f[j]; }
  int inc = s;
  #pragma unroll
  for (int off = 1; off < 64; off <<= 1) {
    int v = __shfl_up(inc, off);
    if (lane >= off) inc += v;
  }
  if (lane == 63) wtot[wid] = inc;
  __syncthreads();
  if (t == 0) {
    int acc = 0;
    for (int w = 0; w < 16; ++w) { wpre[w] = acc; acc += wtot[w]; }
    count[b] = acc;
  }
  __syncthreads();
  int p = wpre[wid] + inc - s;
  #pragma unroll
  for (int j = 0; j < 4; ++j) {
    int g = t * 4 + j;
    if (f[j]) {
      compact[b * S_ + p] = g;
      posmap[b * S_ + g] = p;
      ++p;
    }
  }
}

// ---- fused GEMM (+in-block K-split) + cross-half reduce + top-4 + softmax ----
// BM=32, 4 waves: waves {0,1} K in [0,1024), waves {2,3} K in [1024,2048).
// R6-proven loop structure: gload_lds + __syncthreads, single buffer per half.
__launch_bounds__(256)
__global__ void fused_gemm_topk(const float* __restrict__ A,      // [8][4096][2048]
                                const u16* __restrict__ WhiT,     // [64][2048]
                                const u16* __restrict__ WloT,
                                const int* __restrict__ compact,  // [8][4096]
                                const int* __restrict__ count,    // [8]
                                float* __restrict__ mask) {       // [8][4096][64]
  __shared__ __align__(16) float Ah[2][BM * BK];     // 2 x 8 KB (XOR-swizzled)
  __shared__ __align__(16) u16  Whs[2][E_ * BK];     // 2 x 8 KB
  __shared__ __align__(16) u16  Wls[2][E_ * BK];     // 2 x 8 KB

  const int b    = blockIdx.x >> 7;      // 8 batches x 128 tiles
  const int tile = blockIdx.x & 127;
  const int row0 = tile * BM;
  const int cnt  = count[b];
  if (row0 >= cnt) return;

  const int t    = threadIdx.x;
  const int lane = t & 63;
  const int wid  = t >> 6;
  const int fr   = lane & 15;
  const int fk   = lane >> 4;            // 0..3 (k-subgroup)
  const int half = t >> 7;               // this thread stages+computes half
  const int pt   = t & 127;
  const int kbeg = half * KHALF;

  // --- A staging sources (pre-swizzled global addr; LDS dest linear) ---
  // slot = s*128+pt covers LDS bytes slot*16: row = slot>>4, phys 16B-slot = slot&15,
  // logical slot l = (slot&15) ^ (row&7)
  const float* asrc[4];
  #pragma unroll
  for (int s = 0; s < 4; ++s) {
    int slot = s * 128 + pt;
    int row  = slot >> 4;
    int l    = (slot & 15) ^ (row & 7);
    int rr   = row0 + row; if (rr >= cnt) rr = cnt - 1;
    int grow = compact[b * S_ + rr];
    asrc[s] = A + ((size_t)b * S_ + grow) * D_ + kbeg + l * 4;
  }
  // --- W staging sources: e-row = 128B = 8 slots; l = (slot&7) ^ (e&7) ---
  const u16* whsrc[4];
  const u16* wlsrc[4];
  #pragma unroll
  for (int s = 0; s < 4; ++s) {
    int slot = s * 128 + pt;
    int e    = slot >> 3;
    int l    = (slot & 7) ^ (e & 7);
    whsrc[s] = WhiT + (size_t)e * D_ + kbeg + l * 8;
    wlsrc[s] = WloT + (size_t)e * D_ + kbeg + l * 8;
  }

  // --- LDS read byte offsets (swizzled), static across k-iters ---
  const int arow = (wid & 1) * 16 + fr;
  const int axr  = (arow & 7) << 4;
  u32 aoff[2][2];
  #pragma unroll
  for (int ks = 0; ks < 2; ++ks) {
    aoff[ks][0] = arow * 256 + ((ks * 128 + fk * 32) ^ axr);
    aoff[ks][1] = arow * 256 + ((ks * 128 + fk * 32 + 16) ^ axr);
  }
  u32 woff[2][4];
  #pragma unroll
  for (int n = 0; n < 4; ++n) {
    int e  = n * 16 + fr;
    int xe = (e & 7) << 4;
    #pragma unroll
    for (int ks = 0; ks < 2; ++ks)
      woff[ks][n] = e * 128 + ((ks * 64 + fk * 16) ^ xe);
  }

  f32x4 acc[4] = {};
  const char* aL = (const char*)Ah[half];
  const char* hL = (const char*)Whs[half];
  const char* lL = (const char*)Wls[half];

  for (int tt = 0; tt < NT; ++tt) {
    const int koff = tt * BK;
    // stage this half's tile (single buffer; prior compute done at loop-tail barrier)
    #pragma unroll
    for (int s = 0; s < 4; ++s)
      gload16(asrc[s] + koff, (char*)Ah[half] + (size_t)(s * 128 + pt) * 16);
    #pragma unroll
    for (int s = 0; s < 4; ++s) {
      gload16(whsrc[s] + koff, (char*)Whs[half] + (size_t)(s * 128 + pt) * 16);
      gload16(wlsrc[s] + koff, (char*)Wls[half] + (size_t)(s * 128 + pt) * 16);
    }
    __syncthreads();   // compiler drains vmcnt(0) before s_barrier

    #pragma unroll
    for (int ks = 0; ks < 2; ++ks) {
      f32x4 af0 = *(const f32x4*)(aL + aoff[ks][0]);
      f32x4 af1 = *(const f32x4*)(aL + aoff[ks][1]);
      s16x8 ah, al;
      split8v(af0, af1, ah, al);
      #pragma unroll
      for (int n = 0; n < 4; ++n) {
        s16x8 wh = *(const s16x8*)(hL + woff[ks][n]);
        s16x8 wl = *(const s16x8*)(lL + woff[ks][n]);
        acc[n] = mfma16(al, wh, acc[n]);
        acc[n] = mfma16(ah, wl, acc[n]);
        acc[n] = mfma16(ah, wh, acc[n]);
      }
    }
    __syncthreads();
  }

  // ---- cross-half reduce: waves 2,3 write partials into LDS, waves 0,1 add ----
  // C/D layout: col = n*16 + fr, local row = (lane>>4)*4 + r  (16 rows per wave)
  float* Pr = &Ah[0][0];   // 8 KB scratch (2 x 16 x 64 f32), safe after final barrier
  if (wid >= 2) {
    #pragma unroll
    for (int n = 0; n < 4; ++n)
      #pragma unroll
      for (int r = 0; r < 4; ++r)
        Pr[(wid & 1) * 1024 + ((lane >> 4) * 4 + r) * 64 + n * 16 + fr] = acc[n][r];
  }
  __syncthreads();
  if (wid < 2) {
    #pragma unroll
    for (int n = 0; n < 4; ++n)
      #pragma unroll
      for (int r = 0; r < 4; ++r)
        acc[n][r] += Pr[wid * 1024 + ((lane >> 4) * 4 + r) * 64 + n * 16 + fr];

    // ---- per-row top-4 + softmax, write mask row (16-lane-group reduce) ----
    #pragma unroll
    for (int r = 0; r < 4; ++r) {
      float rv[4]; int ri[4];
      #pragma unroll
      for (int n = 0; n < 4; ++n) { rv[n] = acc[n][r]; ri[n] = n * 16 + fr; }
      float vals[4]; int inds[4];
      #pragma unroll
      for (int tk = 0; tk < 4; ++tk) {
        float mv = rv[0]; int mi = ri[0];
        #pragma unroll
        for (int n = 1; n < 4; ++n)
          if (rv[n] > mv || (rv[n] == mv && ri[n] < mi)) { mv = rv[n]; mi = ri[n]; }
        #pragma unroll
        for (int off = 8; off > 0; off >>= 1) {     // reduce within 16-lane group
          float ov = __shfl_xor(mv, off);
          int   oi = __shfl_xor(mi, off);
          if (ov > mv || (ov == mv && oi < mi)) { mv = ov; mi = oi; }  // tie->smaller idx
        }
        vals[tk] = mv; inds[tk] = mi;
        #pragma unroll
        for (int n = 0; n < 4; ++n) if (ri[n] == mi) rv[n] = -INFINITY;
      }
      float w[4], ssum = 0.f;
      #pragma unroll
      for (int tk = 0; tk < 4; ++tk) { w[tk] = __expf(vals[tk] - vals[0]); ssum += w[tk]; }
      float inv = 1.f / ssum;

      int mrow = row0 + wid * 16 + (lane >> 4) * 4 + r;
      float* mr = mask + ((size_t)b * S_ + mrow) * E_;
      #pragma unroll
      for (int n = 0; n < 4; ++n) {
        int col = n * 16 + fr;
        float o = 0.f;
        #pragma unroll
        for (int tk = 0; tk < 4; ++tk) if (col == inds[tk]) o = w[tk] * inv;
        mr[col] = o;
      }
    }
  }
}

// ---------------- scatter: out[r] = mask[b][posmap[idxs[r]]] ----------------
__launch_bounds__(256)
__global__ void scatter_kernel(const float* __restrict__ mask,   // [8][4096][64]
                               const int* __restrict__ idxs,     // [8][4096]
                               const int* __restrict__ posmap,   // [8][4096]
                               float* __restrict__ out) {        // [8][4096][64]
  const int lane = threadIdx.x & 63;
  const int wid  = threadIdx.x >> 6;
  const int r    = blockIdx.x * 4 + wid;
  const int b    = r >> 12;
  const int p    = posmap[(size_t)b * S_ + idxs[r]];
  out[(size_t)r * E_ + lane] = mask[((size_t)b * S_ + p) * E_ + lane];
}

// ---------------- host ----------------
extern "C" void kernel_launch(void* const* d_in, const int* in_sizes, int n_in,
                              void* d_out, int out_size, void* d_ws, size_t ws_size,
                              hipStream_t stream) {
  const float* hidden = (const float*)d_in[0];
  const int*   idxs   = (const int*)d_in[1];
  const float* W      = (const float*)d_in[2];
  float* out = (float*)d_out;

  // ws: mask (8MB) | WhiT (256KB) | WloT (256KB) | compact (128KB) | posmap (128KB) | count
  char* wsp = (char*)d_ws;
  float* mask = (float*)wsp;                     wsp += (size_t)M_ * E_ * 4;
  u16* whiT = (u16*)wsp;                         wsp += (size_t)E_ * D_ * 2;
  u16* wloT = (u16*)wsp;                         wsp += (size_t)E_ * D_ * 2;
  int* compact = (int*)wsp;                      wsp += (size_t)M_ * 4;
  int* posmap  = (int*)wsp;                      wsp += (size_t)M_ * 4;
  int* count   = (int*)wsp;

  prep_kernel<<<8 + (D_ * E_) / 1024, 1024, 0, stream>>>(W, whiT, wloT, idxs,
                                                          compact, posmap, count);
  fused_gemm_topk<<<B_ * 128, 256, 0, stream>>>(hidden, whiT, wloT, compact, count, mask);
  scatter_kernel<<<M_ / 4, 256, 0, stream>>>(mask, idxs, posmap, out);
}